// Round 4
// baseline (1372.371 us; speedup 1.0000x reference)
//
#include <hip/hip_runtime.h>
#include <float.h>
#include <math.h>

#define NROWS 512
#define DIM 1024
#define NTRAIN 100000
#define MAXK 200
#define NCLS 1000
#define CAP 512        // finalize working set
#define CAP2 4096      // candidate list per row
#define BBCAP 3072
#define INV_T (1.0f/0.07f)
#define C0 8192        // exact-select prefix columns
#define NKS (DIM/32)   // 32 K-steps of BK=32

typedef _Float16 f16x8 __attribute__((ext_vector_type(8)));
typedef _Float16 f16x4 __attribute__((ext_vector_type(4)));
typedef float f32x4 __attribute__((ext_vector_type(4)));

__device__ __forceinline__ unsigned fkey(float f) {
    unsigned u = __float_as_uint(f);
    return (u & 0x80000000u) ? ~u : (u | 0x80000000u);
}
__device__ __forceinline__ float inv_fkey(unsigned k) {
    return (k & 0x80000000u) ? __uint_as_float(k & 0x7fffffffu)
                             : __uint_as_float(~k);
}
__device__ __forceinline__ void gl_lds16(const void* g, void* l) {
    __builtin_amdgcn_global_load_lds(
        (const __attribute__((address_space(1))) unsigned int*)g,
        (__attribute__((address_space(3))) unsigned int*)l, 16, 0, 0);
}

// ---------------- fp32 -> f16 hi/lo split (A and B, pre-converted) ----------------
__global__ __launch_bounds__(256) void convert_split(
    const float* __restrict__ in, _Float16* __restrict__ hi,
    _Float16* __restrict__ lo, long long n)
{
    long long i0 = ((long long)blockIdx.x * 256 + threadIdx.x) * 4;
    long long stride = (long long)gridDim.x * 1024;
    for (long long i = i0; i < n; i += stride) {
        float4 v = *reinterpret_cast<const float4*>(&in[i]);
        float vv[4] = {v.x, v.y, v.z, v.w};
        f16x4 h, l;
        #pragma unroll
        for (int j = 0; j < 4; ++j) {
            _Float16 hh = (_Float16)vv[j];
            h[j] = hh;
            l[j] = (_Float16)(vv[j] - (float)hh);
        }
        *reinterpret_cast<f16x4*>(&hi[i]) = h;
        *reinterpret_cast<f16x4*>(&lo[i]) = l;
    }
}

// ---------------- 3-term split GEMM, m97 schedule ----------------
// 128x128 tile, BK=32, 4 waves (64x64 each), single-buffered 32KB LDS,
// stage -> barrier -> compute -> barrier. Slot-major LDS (conflict-free b128):
// element (row, k) at chunk = (k/8)*128 + row, byte chunk*16 + (k%8)*2.
__global__ __launch_bounds__(256) void gemm3(
    const _Float16* __restrict__ Ah, const _Float16* __restrict__ Al,
    const _Float16* __restrict__ Bh, const _Float16* __restrict__ Bl,
    float* __restrict__ sims, int sstride,
    int chunk_start, int cvalid, int materialize, const float* __restrict__ L,
    float* __restrict__ cv, int* __restrict__ ci, int* __restrict__ cc)
{
    __shared__ __align__(16) _Float16 sAh[4096];   // 8KB each
    __shared__ __align__(16) _Float16 sAl[4096];
    __shared__ __align__(16) _Float16 sBh[4096];
    __shared__ __align__(16) _Float16 sBl[4096];
    const int tid = threadIdx.x;
    const int lane = tid & 63;
    const int wave = tid >> 6;

    // bijective XCD swizzle (grid % 8 == 0), m-tile fastest for B-panel reuse
    const int nwg = gridDim.x;
    const int wg = (blockIdx.x & 7) * (nwg >> 3) + (blockIdx.x >> 3);
    const int mt = wg & 3, nt = wg >> 2;
    const int m0 = mt * 128, n0 = nt * 128;
    const int wm = wave >> 1, wn = wave & 1;

    // staging: 512 chunks of 16B per array; chunk c -> slot=c>>7, row=c&127.
    // LDS dest is wave-uniform base + lane*16 (linear); global src per-lane.
    const int c0s = wave * 64;           // i=0 chunk base for this wave
    const int c1s = wave * 64 + 256;     // i=1 chunk base
    const int r0 = (c0s + lane) & 127, s0 = (c0s + lane) >> 7;
    const int r1 = (c1s + lane) & 127, s1 = (c1s + lane) >> 7;
    const size_t ga0 = (size_t)(m0 + r0) * DIM + s0 * 8;
    const size_t ga1 = (size_t)(m0 + r1) * DIM + s1 * 8;
    int bc0 = chunk_start + n0 + r0; if (bc0 > NTRAIN - 1) bc0 = NTRAIN - 1;
    int bc1 = chunk_start + n0 + r1; if (bc1 > NTRAIN - 1) bc1 = NTRAIN - 1;
    const size_t gb0 = (size_t)bc0 * DIM + s0 * 8;
    const size_t gb1 = (size_t)bc1 * DIM + s1 * 8;

    f32x4 acc[4][4] = {};

    const int slot = lane >> 4;
    const int rA = lane & 15;

    for (int t = 0; t < NKS; ++t) {
        const int k0 = t * 32;
        gl_lds16(Ah + ga0 + k0, (char*)sAh + c0s * 16);
        gl_lds16(Ah + ga1 + k0, (char*)sAh + c1s * 16);
        gl_lds16(Al + ga0 + k0, (char*)sAl + c0s * 16);
        gl_lds16(Al + ga1 + k0, (char*)sAl + c1s * 16);
        gl_lds16(Bh + gb0 + k0, (char*)sBh + c0s * 16);
        gl_lds16(Bh + gb1 + k0, (char*)sBh + c1s * 16);
        gl_lds16(Bl + gb0 + k0, (char*)sBl + c0s * 16);
        gl_lds16(Bl + gb1 + k0, (char*)sBl + c1s * 16);
        __syncthreads();   // drains vmcnt -> tiles resident

        f16x8 bh[4], bl[4];
        #pragma unroll
        for (int n = 0; n < 4; ++n) {
            int ccol = wn * 64 + n * 16 + rA;
            bh[n] = *reinterpret_cast<const f16x8*>(&sBh[(slot * 128 + ccol) * 8]);
            bl[n] = *reinterpret_cast<const f16x8*>(&sBl[(slot * 128 + ccol) * 8]);
        }
        #pragma unroll
        for (int m = 0; m < 4; ++m) {
            int rr = wm * 64 + m * 16 + rA;
            f16x8 ah = *reinterpret_cast<const f16x8*>(&sAh[(slot * 128 + rr) * 8]);
            f16x8 al = *reinterpret_cast<const f16x8*>(&sAl[(slot * 128 + rr) * 8]);
            #pragma unroll
            for (int n = 0; n < 4; ++n) {
                acc[m][n] = __builtin_amdgcn_mfma_f32_16x16x32_f16(ah, bh[n], acc[m][n], 0, 0, 0);
                acc[m][n] = __builtin_amdgcn_mfma_f32_16x16x32_f16(ah, bl[n], acc[m][n], 0, 0, 0);
                acc[m][n] = __builtin_amdgcn_mfma_f32_16x16x32_f16(al, bh[n], acc[m][n], 0, 0, 0);
            }
        }
        __syncthreads();   // protect LDS before next stage
    }

    // epilogue: C/D layout col=lane&15, row=(lane>>4)*4+reg
    const int q4 = (lane >> 4) * 4;
    const int cL = lane & 15;
    if (materialize) {
        #pragma unroll
        for (int m = 0; m < 4; ++m)
            #pragma unroll
            for (int j = 0; j < 4; ++j) {
                int orow = m0 + wm * 64 + m * 16 + q4 + j;
                float* dst = sims + (size_t)orow * sstride + n0 + wn * 64 + cL;
                #pragma unroll
                for (int n = 0; n < 4; ++n)
                    dst[n * 16] = acc[m][n][j];
            }
    } else {
        #pragma unroll
        for (int m = 0; m < 4; ++m)
            #pragma unroll
            for (int j = 0; j < 4; ++j) {
                int orow = m0 + wm * 64 + m * 16 + q4 + j;
                float Lr = L[orow];
                #pragma unroll
                for (int n = 0; n < 4; ++n) {
                    float v = acc[m][n][j];
                    int ocol = n0 + wn * 64 + n * 16 + cL;
                    if (ocol < cvalid && v >= Lr) {
                        int p = atomicAdd(&cc[orow], 1);
                        if (p < CAP2) {
                            cv[(size_t)orow * CAP2 + p] = v;
                            ci[(size_t)orow * CAP2 + p] = chunk_start + ocol;
                        }
                    }
                }
            }
    }
}

// ---------------- exact radix select on first C0 cols; seeds candidates + threshold L ----------------
__global__ __launch_bounds__(256) void select0(
    const float* __restrict__ sims, float* __restrict__ cv, int* __restrict__ ci,
    int* __restrict__ cc, float* __restrict__ L)
{
    __shared__ int hist[2048];
    __shared__ float bbv[BBCAP];
    __shared__ int bbi[BBCAP];
    __shared__ int s_binB, s_above, s_ccnt, s_bcnt, s_binB2;
    const int tid = threadIdx.x;
    const int r = blockIdx.x;
    const float* srow = sims + (size_t)r * C0;

    for (int i = tid; i < 2048; i += 256) hist[i] = 0;
    if (tid == 0) { s_ccnt = 0; s_bcnt = 0; }
    __syncthreads();

    for (int i = tid; i < C0; i += 256)
        atomicAdd(&hist[fkey(srow[i]) >> 21], 1);
    __syncthreads();
    if (tid == 0) {
        int cum = 0, b = 2047;
        for (; b > 0; --b) { if (cum + hist[b] >= MAXK) break; cum += hist[b]; }
        s_binB = b; s_above = cum;
    }
    __syncthreads();
    const int binB = s_binB;

    for (int i = tid; i < C0; i += 256) {
        float v = srow[i];
        int b = (int)(fkey(v) >> 21);
        if (b > binB) {
            int p = atomicAdd(&s_ccnt, 1);
            if (p < CAP2) { cv[(size_t)r * CAP2 + p] = v; ci[(size_t)r * CAP2 + p] = i; }
        } else if (b == binB) {
            int p = atomicAdd(&s_bcnt, 1);
            if (p < BBCAP) { bbv[p] = v; bbi[p] = i; }
        }
    }
    __syncthreads();
    const int bcnt = min(s_bcnt, BBCAP);
    const int need = MAXK - s_above;

    for (int i = tid; i < 2048; i += 256) hist[i] = 0;
    __syncthreads();
    for (int i = tid; i < bcnt; i += 256)
        atomicAdd(&hist[(fkey(bbv[i]) >> 10) & 0x7FF], 1);
    __syncthreads();
    if (tid == 0) {
        int cum = 0, b = 2047;
        for (; b > 0; --b) { if (cum + hist[b] >= need) break; cum += hist[b]; }
        s_binB2 = b;
    }
    __syncthreads();
    const int binB2 = s_binB2;
    for (int i = tid; i < bcnt; i += 256) {
        int sub = (int)((fkey(bbv[i]) >> 10) & 0x7FF);
        if (sub >= binB2) {
            int p = atomicAdd(&s_ccnt, 1);
            if (p < CAP2) { cv[(size_t)r * CAP2 + p] = bbv[i]; ci[(size_t)r * CAP2 + p] = bbi[i]; }
        }
    }
    __syncthreads();
    if (tid == 0) {
        cc[r] = min(s_ccnt, CAP2);
        unsigned edge = ((unsigned)binB << 21) | ((unsigned)binB2 << 10);
        L[r] = inv_fkey(edge);   // all kept values >= L; filter keeps v >= L
    }
}

// ---------------- final: radix-select top-200 superset, sort, softmax, cumulative scatter ----------------
__global__ __launch_bounds__(256) void finalize2(
    const float* __restrict__ cv, const int* __restrict__ ci, const int* __restrict__ cc,
    const int* __restrict__ labels, float* __restrict__ out)
{
    __shared__ int hist[2048];
    __shared__ float sval[CAP];
    __shared__ int   sidx[CAP];
    __shared__ float bbv[BBCAP];
    __shared__ int   bbi[BBCAP];
    __shared__ float cls[NCLS];
    __shared__ float s_sum;
    __shared__ int s_binB, s_above, s_cnt, s_bcnt, s_binB2;
    const int tid = threadIdx.x;
    const int r = blockIdx.x;
    const int M = min(cc[r], CAP2);
    const float* cvr = cv + (size_t)r * CAP2;
    const int*   cir = ci + (size_t)r * CAP2;

    for (int i = tid; i < 2048; i += 256) hist[i] = 0;
    if (tid == 0) { s_cnt = 0; s_bcnt = 0; }
    __syncthreads();
    for (int i = tid; i < M; i += 256)
        atomicAdd(&hist[fkey(cvr[i]) >> 21], 1);
    __syncthreads();
    if (tid == 0) {
        int cum = 0, b = 2047;
        for (; b > 0; --b) { if (cum + hist[b] >= MAXK) break; cum += hist[b]; }
        s_binB = b; s_above = cum;
    }
    __syncthreads();
    const int binB = s_binB;

    for (int i = tid; i < M; i += 256) {
        float v = cvr[i];
        int b = (int)(fkey(v) >> 21);
        if (b > binB) {
            int p = atomicAdd(&s_cnt, 1);
            if (p < CAP) { sval[p] = v; sidx[p] = cir[i]; }
        } else if (b == binB) {
            int p = atomicAdd(&s_bcnt, 1);
            if (p < BBCAP) { bbv[p] = v; bbi[p] = cir[i]; }
        }
    }
    __syncthreads();
    const int bcnt = min(s_bcnt, BBCAP);
    const int need = MAXK - s_above;
    for (int i = tid; i < 2048; i += 256) hist[i] = 0;
    __syncthreads();
    for (int i = tid; i < bcnt; i += 256)
        atomicAdd(&hist[(fkey(bbv[i]) >> 10) & 0x7FF], 1);
    __syncthreads();
    if (tid == 0) {
        int cum = 0, b = 2047;
        for (; b > 0; --b) { if (cum + hist[b] >= need) break; cum += hist[b]; }
        s_binB2 = b;
    }
    __syncthreads();
    const int binB2 = s_binB2;
    for (int i = tid; i < bcnt; i += 256) {
        int sub = (int)((fkey(bbv[i]) >> 10) & 0x7FF);
        if (sub >= binB2) {
            int p = atomicAdd(&s_cnt, 1);
            if (p < CAP) { sval[p] = bbv[i]; sidx[p] = bbi[i]; }
        }
    }
    __syncthreads();
    const int kept = min(s_cnt, CAP);
    for (int i = kept + tid; i < CAP; i += 256) { sval[i] = -FLT_MAX; sidx[i] = 0x7FFFFFFF; }
    __syncthreads();

    for (int k = 2; k <= CAP; k <<= 1)
        for (int j = k >> 1; j > 0; j >>= 1) {
            for (int i = tid; i < CAP; i += 256) {
                int l = i ^ j;
                if (l > i) {
                    float av = sval[i], bv2 = sval[l];
                    int ai = sidx[i], bi = sidx[l];
                    bool iGTl = (av > bv2) || (av == bv2 && ai < bi);
                    bool sw = ((i & k) == 0) ? (!iGTl) : iGTl;
                    if (sw) { sval[i] = bv2; sval[l] = av; sidx[i] = bi; sidx[l] = ai; }
                }
            }
            __syncthreads();
        }

    float mx = sval[0];
    if (tid == 0) s_sum = 0.f;
    __syncthreads();
    float part = 0.f;
    for (int i = tid; i < MAXK; i += 256) {
        float e = expf((sval[i] - mx) * INV_T);
        sval[i] = e;
        part += e;
    }
    atomicAdd(&s_sum, part);
    __syncthreads();
    float inv = 1.f / s_sum;
    for (int i = tid; i < MAXK; i += 256) {
        sval[i] *= inv;
        sidx[i] = labels[sidx[i]];
    }
    for (int c = tid; c < NCLS; c += 256) cls[c] = 0.f;
    __syncthreads();

    const int KS[4] = {10, 20, 100, 200};
    int prev = 0;
    for (int s = 0; s < 4; ++s) {
        for (int i = prev + tid; i < KS[s]; i += 256)
            atomicAdd(&cls[sidx[i]], sval[i]);
        __syncthreads();
        float* o = out + ((size_t)s * NROWS + r) * NCLS;
        for (int c = tid; c < NCLS; c += 256) o[c] = cls[c];
        __syncthreads();
        prev = KS[s];
    }
}

// ---------------- host launcher ----------------
extern "C" void kernel_launch(void* const* d_in, const int* in_sizes, int n_in,
                              void* d_out, int out_size, void* d_ws, size_t ws_size,
                              hipStream_t stream)
{
    const float* A = (const float*)d_in[0];       // [512,1024]
    const float* B = (const float*)d_in[1];       // [100000,1024]
    const int* labels = (const int*)d_in[2];      // [100000]
    float* out = (float*)d_out;                   // [4,512,1000] f32

    char* ws = (char*)d_ws;
    size_t off = 0;
    auto carve = [&](size_t bytes) -> void* {
        void* p = ws + off;
        off = (off + bytes + 255) & ~(size_t)255;
        return p;
    };
    _Float16* Ah = (_Float16*)carve((size_t)NROWS * DIM * 2);
    _Float16* Al = (_Float16*)carve((size_t)NROWS * DIM * 2);
    _Float16* Bh = (_Float16*)carve((size_t)NTRAIN * DIM * 2);   // 204.8 MB
    _Float16* Bl = (_Float16*)carve((size_t)NTRAIN * DIM * 2);   // 204.8 MB
    float* cv = (float*)carve((size_t)NROWS * CAP2 * 4);
    int*   ci = (int*)carve((size_t)NROWS * CAP2 * 4);
    int*   cc = (int*)carve((size_t)NROWS * 4);
    float* L  = (float*)carve((size_t)NROWS * 4);
    float* sims = (float*)carve((size_t)NROWS * C0 * 4);

    // pre-split A (1 MB) and B (410 MB) to f16 hi/lo
    convert_split<<<256, 256, 0, stream>>>(A, Ah, Al, (long long)NROWS * DIM);
    convert_split<<<4096, 256, 0, stream>>>(B, Bh, Bl, (long long)NTRAIN * DIM);

    // exact prefix: materialize sims for first C0 cols, radix-select, set threshold L
    gemm3<<<4 * (C0 / 128), 256, 0, stream>>>(Ah, Al, Bh, Bl, sims, C0,
        0, C0, 1, L, cv, ci, cc);
    select0<<<NROWS, 256, 0, stream>>>(sims, cv, ci, cc, L);

    // single filtered pass over remaining columns
    int cval = NTRAIN - C0;                       // 91808
    int nt2 = (cval + 127) / 128;                 // 718 -> grid 2872 (div by 8)
    gemm3<<<4 * nt2, 256, 0, stream>>>(Ah, Al, Bh, Bl, nullptr, 0,
        C0, cval, 0, L, cv, ci, cc);

    finalize2<<<NROWS, 256, 0, stream>>>(cv, ci, cc, labels, out);
}

// Round 5
// 1223.331 us; speedup vs baseline: 1.1218x; 1.1218x over previous
//
#include <hip/hip_runtime.h>
#include <float.h>
#include <math.h>

#define NROWS 512
#define DIM 1024
#define NTRAIN 100000
#define MAXK 200
#define NCLS 1000
#define CAP 512        // finalize working set
#define CAP2 4096      // candidate list per row
#define BBCAP 3072
#define INV_T (1.0f/0.07f)
#define C0 8192        // exact-select prefix columns
#define NKS (DIM/32)   // 32 K-steps of BK=32

typedef _Float16 f16x8 __attribute__((ext_vector_type(8)));
typedef _Float16 f16x4 __attribute__((ext_vector_type(4)));
typedef float f32x4 __attribute__((ext_vector_type(4)));

__device__ __forceinline__ unsigned fkey(float f) {
    unsigned u = __float_as_uint(f);
    return (u & 0x80000000u) ? ~u : (u | 0x80000000u);
}
__device__ __forceinline__ float inv_fkey(unsigned k) {
    return (k & 0x80000000u) ? __uint_as_float(k & 0x7fffffffu)
                             : __uint_as_float(~k);
}
__device__ __forceinline__ void gl_lds16(const void* g, void* l) {
    __builtin_amdgcn_global_load_lds(
        (const __attribute__((address_space(1))) unsigned int*)g,
        (__attribute__((address_space(3))) unsigned int*)l, 16, 0, 0);
}

// ---------------- fp32 -> f16 hi/lo split (A and B, pre-converted) ----------------
__global__ __launch_bounds__(256) void convert_split(
    const float* __restrict__ in, _Float16* __restrict__ hi,
    _Float16* __restrict__ lo, long long n)
{
    long long i0 = ((long long)blockIdx.x * 256 + threadIdx.x) * 4;
    long long stride = (long long)gridDim.x * 1024;
    for (long long i = i0; i < n; i += stride) {
        float4 v = *reinterpret_cast<const float4*>(&in[i]);
        float vv[4] = {v.x, v.y, v.z, v.w};
        f16x4 h, l;
        #pragma unroll
        for (int j = 0; j < 4; ++j) {
            _Float16 hh = (_Float16)vv[j];
            h[j] = hh;
            l[j] = (_Float16)(vv[j] - (float)hh);
        }
        *reinterpret_cast<f16x4*>(&hi[i]) = h;
        *reinterpret_cast<f16x4*>(&lo[i]) = l;
    }
}

// ---------------- 3-term split GEMM, 2-phase double-buffered pipeline ----------------
// 128x128 tile, BK=32, 4 waves (64x64 each), 64KB LDS (2 bufs x 4 arrays x 8KB).
// LDS tile layout per array: chunk c in [0,512), 16B each; c = rr*4 + (slot ^ ((rr>>1)&3)),
// rr = row 0..127, slot = k-quarter (8 f16). Staging: 4 consecutive lanes = one 64B
// row-line (fully packed, 16 lines/instr). Frag ds_read_b128: 2-way bank alias max.
template <int MATERIALIZE>
__global__ __launch_bounds__(256) void gemm3(
    const _Float16* __restrict__ Ah, const _Float16* __restrict__ Al,
    const _Float16* __restrict__ Bh, const _Float16* __restrict__ Bl,
    float* __restrict__ sims, int sstride,
    int chunk_start, int cvalid, const float* __restrict__ L,
    float* __restrict__ cv, int* __restrict__ ci, int* __restrict__ cc)
{
    __shared__ __align__(16) _Float16 sm[2][4][4096];   // [buf][Ah,Al,Bh,Bl][8KB]
    const int tid = threadIdx.x;
    const int lane = tid & 63;
    const int wave = tid >> 6;

    // bijective XCD swizzle (grid % 8 == 0), m-tile fastest for B-panel L2 reuse
    const int nwg = gridDim.x;
    const int wg = (blockIdx.x & 7) * (nwg >> 3) + (blockIdx.x >> 3);
    const int mt = wg & 3, nt = wg >> 2;
    const int m0 = mt * 128, n0 = nt * 128;
    const int wm = wave >> 1, wn = wave & 1;

    // staging geometry: instr i covers chunks [wave*64 + i*256, +64); lane -> base+lane
    size_t gA[2], gB[2];
    #pragma unroll
    for (int i = 0; i < 2; ++i) {
        int c = wave * 64 + i * 256 + lane;
        int rr = c >> 2, q = c & 3;
        int slot = q ^ ((rr >> 1) & 3);
        int brow = chunk_start + n0 + rr;
        if (brow > NTRAIN - 1) brow = NTRAIN - 1;
        gA[i] = (size_t)(m0 + rr) * DIM + slot * 8;
        gB[i] = (size_t)brow * DIM + slot * 8;
    }
    const int ldsb0 = (wave * 64) * 16;
    const int ldsb1 = (wave * 64 + 256) * 16;

    f32x4 acc[4][4] = {};

    auto stage = [&](int b, int k0) {
        char* base = (char*)&sm[b][0][0];
        gl_lds16(Ah + gA[0] + k0, base + 0 * 8192 + ldsb0);
        gl_lds16(Ah + gA[1] + k0, base + 0 * 8192 + ldsb1);
        gl_lds16(Al + gA[0] + k0, base + 1 * 8192 + ldsb0);
        gl_lds16(Al + gA[1] + k0, base + 1 * 8192 + ldsb1);
        gl_lds16(Bh + gB[0] + k0, base + 2 * 8192 + ldsb0);
        gl_lds16(Bh + gB[1] + k0, base + 2 * 8192 + ldsb1);
        gl_lds16(Bl + gB[0] + k0, base + 3 * 8192 + ldsb0);
        gl_lds16(Bl + gB[1] + k0, base + 3 * 8192 + ldsb1);
    };

    const int slot = lane >> 4;
    const int r16 = lane & 15;

    // prologue
    stage(0, 0);
    __syncthreads();

    for (int t = 0; t < NKS; ++t) {
        const int b = t & 1;
        if (t + 1 < NKS) stage(b ^ 1, (t + 1) * 32);   // prefetch next K-step

        const _Float16* sa_h = &sm[b][0][0];
        const _Float16* sa_l = &sm[b][1][0];
        const _Float16* sb_h = &sm[b][2][0];
        const _Float16* sb_l = &sm[b][3][0];

        f16x8 bhv[4], blv[4];
        #pragma unroll
        for (int n = 0; n < 4; ++n) {
            int rr = wn * 64 + n * 16 + r16;
            int cch = rr * 4 + (slot ^ ((rr >> 1) & 3));
            bhv[n] = *reinterpret_cast<const f16x8*>(&sb_h[cch * 8]);
            blv[n] = *reinterpret_cast<const f16x8*>(&sb_l[cch * 8]);
        }
        #pragma unroll
        for (int m = 0; m < 4; ++m) {
            int rr = wm * 64 + m * 16 + r16;
            int cch = rr * 4 + (slot ^ ((rr >> 1) & 3));
            f16x8 ahv = *reinterpret_cast<const f16x8*>(&sa_h[cch * 8]);
            f16x8 alv = *reinterpret_cast<const f16x8*>(&sa_l[cch * 8]);
            #pragma unroll
            for (int n = 0; n < 4; ++n) {
                acc[m][n] = __builtin_amdgcn_mfma_f32_16x16x32_f16(ahv, bhv[n], acc[m][n], 0, 0, 0);
                acc[m][n] = __builtin_amdgcn_mfma_f32_16x16x32_f16(ahv, blv[n], acc[m][n], 0, 0, 0);
                acc[m][n] = __builtin_amdgcn_mfma_f32_16x16x32_f16(alv, bhv[n], acc[m][n], 0, 0, 0);
            }
        }
        __syncthreads();   // drains prefetch vmcnt + protects buffers
    }

    // epilogue: C/D layout col=lane&15, row=(lane>>4)*4+reg
    const int q4 = (lane >> 4) * 4;
    const int cL = lane & 15;
    if (MATERIALIZE) {
        #pragma unroll
        for (int m = 0; m < 4; ++m)
            #pragma unroll
            for (int j = 0; j < 4; ++j) {
                int orow = m0 + wm * 64 + m * 16 + q4 + j;
                float* dst = sims + (size_t)orow * sstride + n0 + wn * 64 + cL;
                #pragma unroll
                for (int n = 0; n < 4; ++n)
                    dst[n * 16] = acc[m][n][j];
            }
    } else {
        #pragma unroll
        for (int m = 0; m < 4; ++m)
            #pragma unroll
            for (int j = 0; j < 4; ++j) {
                int orow = m0 + wm * 64 + m * 16 + q4 + j;
                float Lr = L[orow];
                #pragma unroll
                for (int n = 0; n < 4; ++n) {
                    float v = acc[m][n][j];
                    int ocol = n0 + wn * 64 + n * 16 + cL;
                    if (ocol < cvalid && v >= Lr) {
                        int p = atomicAdd(&cc[orow], 1);
                        if (p < CAP2) {
                            cv[(size_t)orow * CAP2 + p] = v;
                            ci[(size_t)orow * CAP2 + p] = chunk_start + ocol;
                        }
                    }
                }
            }
    }
}

// ---------------- exact radix select on first C0 cols; seeds candidates + threshold L ----------------
__global__ __launch_bounds__(256) void select0(
    const float* __restrict__ sims, float* __restrict__ cv, int* __restrict__ ci,
    int* __restrict__ cc, float* __restrict__ L)
{
    __shared__ int hist[2048];
    __shared__ float bbv[BBCAP];
    __shared__ int bbi[BBCAP];
    __shared__ int s_binB, s_above, s_ccnt, s_bcnt, s_binB2;
    const int tid = threadIdx.x;
    const int r = blockIdx.x;
    const float* srow = sims + (size_t)r * C0;

    for (int i = tid; i < 2048; i += 256) hist[i] = 0;
    if (tid == 0) { s_ccnt = 0; s_bcnt = 0; }
    __syncthreads();

    for (int i = tid; i < C0; i += 256)
        atomicAdd(&hist[fkey(srow[i]) >> 21], 1);
    __syncthreads();
    if (tid == 0) {
        int cum = 0, b = 2047;
        for (; b > 0; --b) { if (cum + hist[b] >= MAXK) break; cum += hist[b]; }
        s_binB = b; s_above = cum;
    }
    __syncthreads();
    const int binB = s_binB;

    for (int i = tid; i < C0; i += 256) {
        float v = srow[i];
        int b = (int)(fkey(v) >> 21);
        if (b > binB) {
            int p = atomicAdd(&s_ccnt, 1);
            if (p < CAP2) { cv[(size_t)r * CAP2 + p] = v; ci[(size_t)r * CAP2 + p] = i; }
        } else if (b == binB) {
            int p = atomicAdd(&s_bcnt, 1);
            if (p < BBCAP) { bbv[p] = v; bbi[p] = i; }
        }
    }
    __syncthreads();
    const int bcnt = min(s_bcnt, BBCAP);
    const int need = MAXK - s_above;

    for (int i = tid; i < 2048; i += 256) hist[i] = 0;
    __syncthreads();
    for (int i = tid; i < bcnt; i += 256)
        atomicAdd(&hist[(fkey(bbv[i]) >> 10) & 0x7FF], 1);
    __syncthreads();
    if (tid == 0) {
        int cum = 0, b = 2047;
        for (; b > 0; --b) { if (cum + hist[b] >= need) break; cum += hist[b]; }
        s_binB2 = b;
    }
    __syncthreads();
    const int binB2 = s_binB2;
    for (int i = tid; i < bcnt; i += 256) {
        int sub = (int)((fkey(bbv[i]) >> 10) & 0x7FF);
        if (sub >= binB2) {
            int p = atomicAdd(&s_ccnt, 1);
            if (p < CAP2) { cv[(size_t)r * CAP2 + p] = bbv[i]; ci[(size_t)r * CAP2 + p] = bbi[i]; }
        }
    }
    __syncthreads();
    if (tid == 0) {
        cc[r] = min(s_ccnt, CAP2);
        unsigned edge = ((unsigned)binB << 21) | ((unsigned)binB2 << 10);
        L[r] = inv_fkey(edge);   // all kept values >= L; filter keeps v >= L
    }
}

// ---------------- final: radix-select top-200 superset, sort, softmax, cumulative scatter ----------------
__global__ __launch_bounds__(256) void finalize2(
    const float* __restrict__ cv, const int* __restrict__ ci, const int* __restrict__ cc,
    const int* __restrict__ labels, float* __restrict__ out)
{
    __shared__ int hist[2048];
    __shared__ float sval[CAP];
    __shared__ int   sidx[CAP];
    __shared__ float bbv[BBCAP];
    __shared__ int   bbi[BBCAP];
    __shared__ float cls[NCLS];
    __shared__ float s_sum;
    __shared__ int s_binB, s_above, s_cnt, s_bcnt, s_binB2;
    const int tid = threadIdx.x;
    const int r = blockIdx.x;
    const int M = min(cc[r], CAP2);
    const float* cvr = cv + (size_t)r * CAP2;
    const int*   cir = ci + (size_t)r * CAP2;

    for (int i = tid; i < 2048; i += 256) hist[i] = 0;
    if (tid == 0) { s_cnt = 0; s_bcnt = 0; }
    __syncthreads();
    for (int i = tid; i < M; i += 256)
        atomicAdd(&hist[fkey(cvr[i]) >> 21], 1);
    __syncthreads();
    if (tid == 0) {
        int cum = 0, b = 2047;
        for (; b > 0; --b) { if (cum + hist[b] >= MAXK) break; cum += hist[b]; }
        s_binB = b; s_above = cum;
    }
    __syncthreads();
    const int binB = s_binB;

    for (int i = tid; i < M; i += 256) {
        float v = cvr[i];
        int b = (int)(fkey(v) >> 21);
        if (b > binB) {
            int p = atomicAdd(&s_cnt, 1);
            if (p < CAP) { sval[p] = v; sidx[p] = cir[i]; }
        } else if (b == binB) {
            int p = atomicAdd(&s_bcnt, 1);
            if (p < BBCAP) { bbv[p] = v; bbi[p] = cir[i]; }
        }
    }
    __syncthreads();
    const int bcnt = min(s_bcnt, BBCAP);
    const int need = MAXK - s_above;
    for (int i = tid; i < 2048; i += 256) hist[i] = 0;
    __syncthreads();
    for (int i = tid; i < bcnt; i += 256)
        atomicAdd(&hist[(fkey(bbv[i]) >> 10) & 0x7FF], 1);
    __syncthreads();
    if (tid == 0) {
        int cum = 0, b = 2047;
        for (; b > 0; --b) { if (cum + hist[b] >= need) break; cum += hist[b]; }
        s_binB2 = b;
    }
    __syncthreads();
    const int binB2 = s_binB2;
    for (int i = tid; i < bcnt; i += 256) {
        int sub = (int)((fkey(bbv[i]) >> 10) & 0x7FF);
        if (sub >= binB2) {
            int p = atomicAdd(&s_cnt, 1);
            if (p < CAP) { sval[p] = bbv[i]; sidx[p] = bbi[i]; }
        }
    }
    __syncthreads();
    const int kept = min(s_cnt, CAP);
    for (int i = kept + tid; i < CAP; i += 256) { sval[i] = -FLT_MAX; sidx[i] = 0x7FFFFFFF; }
    __syncthreads();

    for (int k = 2; k <= CAP; k <<= 1)
        for (int j = k >> 1; j > 0; j >>= 1) {
            for (int i = tid; i < CAP; i += 256) {
                int l = i ^ j;
                if (l > i) {
                    float av = sval[i], bv2 = sval[l];
                    int ai = sidx[i], bi = sidx[l];
                    bool iGTl = (av > bv2) || (av == bv2 && ai < bi);
                    bool sw = ((i & k) == 0) ? (!iGTl) : iGTl;
                    if (sw) { sval[i] = bv2; sval[l] = av; sidx[i] = bi; sidx[l] = ai; }
                }
            }
            __syncthreads();
        }

    float mx = sval[0];
    if (tid == 0) s_sum = 0.f;
    __syncthreads();
    float part = 0.f;
    for (int i = tid; i < MAXK; i += 256) {
        float e = expf((sval[i] - mx) * INV_T);
        sval[i] = e;
        part += e;
    }
    atomicAdd(&s_sum, part);
    __syncthreads();
    float inv = 1.f / s_sum;
    for (int i = tid; i < MAXK; i += 256) {
        sval[i] *= inv;
        sidx[i] = labels[sidx[i]];
    }
    for (int c = tid; c < NCLS; c += 256) cls[c] = 0.f;
    __syncthreads();

    const int KS[4] = {10, 20, 100, 200};
    int prev = 0;
    for (int s = 0; s < 4; ++s) {
        for (int i = prev + tid; i < KS[s]; i += 256)
            atomicAdd(&cls[sidx[i]], sval[i]);
        __syncthreads();
        float* o = out + ((size_t)s * NROWS + r) * NCLS;
        for (int c = tid; c < NCLS; c += 256) o[c] = cls[c];
        __syncthreads();
        prev = KS[s];
    }
}

// ---------------- host launcher ----------------
extern "C" void kernel_launch(void* const* d_in, const int* in_sizes, int n_in,
                              void* d_out, int out_size, void* d_ws, size_t ws_size,
                              hipStream_t stream)
{
    const float* A = (const float*)d_in[0];       // [512,1024]
    const float* B = (const float*)d_in[1];       // [100000,1024]
    const int* labels = (const int*)d_in[2];      // [100000]
    float* out = (float*)d_out;                   // [4,512,1000] f32

    char* ws = (char*)d_ws;
    size_t off = 0;
    auto carve = [&](size_t bytes) -> void* {
        void* p = ws + off;
        off = (off + bytes + 255) & ~(size_t)255;
        return p;
    };
    _Float16* Ah = (_Float16*)carve((size_t)NROWS * DIM * 2);
    _Float16* Al = (_Float16*)carve((size_t)NROWS * DIM * 2);
    _Float16* Bh = (_Float16*)carve((size_t)NTRAIN * DIM * 2);   // 204.8 MB
    _Float16* Bl = (_Float16*)carve((size_t)NTRAIN * DIM * 2);   // 204.8 MB
    float* cv = (float*)carve((size_t)NROWS * CAP2 * 4);
    int*   ci = (int*)carve((size_t)NROWS * CAP2 * 4);
    int*   cc = (int*)carve((size_t)NROWS * 4);
    float* L  = (float*)carve((size_t)NROWS * 4);
    float* sims = (float*)carve((size_t)NROWS * C0 * 4);

    // pre-split A (1 MB) and B (410 MB) to f16 hi/lo
    convert_split<<<256, 256, 0, stream>>>(A, Ah, Al, (long long)NROWS * DIM);
    convert_split<<<4096, 256, 0, stream>>>(B, Bh, Bl, (long long)NTRAIN * DIM);

    // exact prefix: materialize sims for first C0 cols, radix-select, set threshold L
    gemm3<1><<<4 * (C0 / 128), 256, 0, stream>>>(Ah, Al, Bh, Bl, sims, C0,
        0, C0, nullptr, nullptr, nullptr, nullptr);
    select0<<<NROWS, 256, 0, stream>>>(sims, cv, ci, cc, L);

    // single filtered pass over remaining columns
    int cval = NTRAIN - C0;                       // 91808
    int nt2 = (cval + 127) / 128;                 // 718 -> grid 2872 (div by 8)
    gemm3<0><<<4 * nt2, 256, 0, stream>>>(Ah, Al, Bh, Bl, nullptr, 0,
        C0, cval, L, cv, ci, cc);

    finalize2<<<NROWS, 256, 0, stream>>>(cv, ci, cc, labels, out);
}

// Round 6
// 501.038 us; speedup vs baseline: 2.7391x; 2.4416x over previous
//
#include <hip/hip_runtime.h>
#include <float.h>
#include <math.h>

#define NROWS 512
#define DIM 1024
#define NTRAIN 100000
#define MAXK 200
#define NCLS 1000
#define CAP 512          // finalize working set
#define CAP2 1024        // candidate list per row (expected ~210)
#define INV_T (1.0f/0.07f)
#define NKS (DIM/32)     // 32 K-steps of BK=32
#define NTILE 784        // ceil(100000/128)
#define NPAD (NTILE*128) // 100352 padded sims stride
#define MARGIN 2.5f      // >= 2*7sigma of bf16 sim error (sigma~0.10)
#define HBINS 2048
#define HLO (-160.0f)
#define HSC 6.4f         // bins of width 0.15625 over [-160,160)

typedef short s16x8 __attribute__((ext_vector_type(8)));
typedef float f32x4 __attribute__((ext_vector_type(4)));

__device__ __forceinline__ void gl_lds16(const void* g, void* l) {
    __builtin_amdgcn_global_load_lds(
        (const __attribute__((address_space(1))) unsigned int*)g,
        (__attribute__((address_space(3))) unsigned int*)l, 16, 0, 0);
}
__device__ __forceinline__ unsigned short f2bf(float x) {   // RTNE
    unsigned u = __float_as_uint(x);
    return (unsigned short)((u + 0x7FFFu + ((u >> 16) & 1u)) >> 16);
}

// ---------------- fp32 -> bf16 ----------------
__global__ __launch_bounds__(256) void convert_bf16(
    const float* __restrict__ in, unsigned short* __restrict__ out, long long n)
{
    long long i0 = ((long long)blockIdx.x * 256 + threadIdx.x) * 4;
    long long stride = (long long)gridDim.x * 1024;
    for (long long i = i0; i < n; i += stride) {
        float4 v = *reinterpret_cast<const float4*>(&in[i]);
        ushort4 o;
        o.x = f2bf(v.x); o.y = f2bf(v.y); o.z = f2bf(v.z); o.w = f2bf(v.w);
        *reinterpret_cast<ushort4*>(&out[i]) = o;
    }
}

// ---------------- single-term bf16 GEMM, materialize all sims ----------------
// 128x128 tile, BK=32, 4 waves (64x64 each), 32KB LDS double-buffered.
// Packed-line staging (4 lanes = one 64B row line) + 2-bit XOR slot swizzle
// (verified conflict-free in r5). One __syncthreads per K-step.
__global__ __launch_bounds__(256) void gemm_bf(
    const unsigned short* __restrict__ Ab, const unsigned short* __restrict__ Bb,
    float* __restrict__ sims)
{
    __shared__ __align__(16) unsigned short sm[2][2][4096];  // [buf][A,B][8KB]
    const int tid = threadIdx.x;
    const int lane = tid & 63;
    const int wave = tid >> 6;

    // bijective XCD swizzle (grid % 8 == 0), m-tile fastest for B-panel L2 reuse
    const int nwg = gridDim.x;
    const int wg = (blockIdx.x & 7) * (nwg >> 3) + (blockIdx.x >> 3);
    const int mt = wg & 3, nt = wg >> 2;
    const int m0 = mt * 128, n0 = nt * 128;
    const int wm = wave >> 1, wn = wave & 1;

    // staging geometry: instr i covers chunks [wave*64 + i*256, +64); lane -> base+lane
    size_t gA[2], gB[2];
    #pragma unroll
    for (int i = 0; i < 2; ++i) {
        int c = wave * 64 + i * 256 + lane;
        int rr = c >> 2, q = c & 3;
        int slot = q ^ ((rr >> 1) & 3);
        int brow = n0 + rr;
        if (brow > NTRAIN - 1) brow = NTRAIN - 1;   // pad cols clamp (ignored later)
        gA[i] = (size_t)(m0 + rr) * DIM + slot * 8;
        gB[i] = (size_t)brow * DIM + slot * 8;
    }
    const int ldsb0 = (wave * 64) * 16;
    const int ldsb1 = (wave * 64 + 256) * 16;

    f32x4 acc[4][4] = {};

    auto stage = [&](int b, int k0) {
        char* base = (char*)&sm[b][0][0];
        gl_lds16(Ab + gA[0] + k0, base + 0 * 8192 + ldsb0);
        gl_lds16(Ab + gA[1] + k0, base + 0 * 8192 + ldsb1);
        gl_lds16(Bb + gB[0] + k0, base + 1 * 8192 + ldsb0);
        gl_lds16(Bb + gB[1] + k0, base + 1 * 8192 + ldsb1);
    };

    const int slot = lane >> 4;
    const int r16 = lane & 15;

    stage(0, 0);
    __syncthreads();

    for (int t = 0; t < NKS; ++t) {
        const int b = t & 1;
        if (t + 1 < NKS) stage(b ^ 1, (t + 1) * 32);   // prefetch next K-step

        const unsigned short* sa = &sm[b][0][0];
        const unsigned short* sb = &sm[b][1][0];

        s16x8 bv[4];
        #pragma unroll
        for (int n = 0; n < 4; ++n) {
            int rr = wn * 64 + n * 16 + r16;
            int cch = rr * 4 + (slot ^ ((rr >> 1) & 3));
            bv[n] = *reinterpret_cast<const s16x8*>(&sb[cch * 8]);
        }
        #pragma unroll
        for (int m = 0; m < 4; ++m) {
            int rr = wm * 64 + m * 16 + r16;
            int cch = rr * 4 + (slot ^ ((rr >> 1) & 3));
            s16x8 av = *reinterpret_cast<const s16x8*>(&sa[cch * 8]);
            #pragma unroll
            for (int n = 0; n < 4; ++n)
                acc[m][n] = __builtin_amdgcn_mfma_f32_16x16x32_bf16(av, bv[n], acc[m][n], 0, 0, 0);
        }
        __syncthreads();   // drains prefetch vmcnt + protects buffers
    }

    // epilogue: C/D layout col=lane&15, row=(lane>>4)*4+reg
    const int q4 = (lane >> 4) * 4;
    const int cL = lane & 15;
    #pragma unroll
    for (int m = 0; m < 4; ++m)
        #pragma unroll
        for (int j = 0; j < 4; ++j) {
            int orow = m0 + wm * 64 + m * 16 + q4 + j;
            float* dst = sims + (size_t)orow * NPAD + n0 + wn * 64 + cL;
            #pragma unroll
            for (int n = 0; n < 4; ++n)
                dst[n * 16] = acc[m][n][j];
        }
}

// ---------------- per-row: flat histogram -> threshold-with-margin -> append ----------------
__global__ __launch_bounds__(256) void select_margin(
    const float* __restrict__ sims, int* __restrict__ ci, int* __restrict__ cc)
{
    __shared__ int hist[4][HBINS];   // 32KB, 4 replicas to cut atomic collisions
    __shared__ float s_L;
    __shared__ int s_cnt;
    const int tid = threadIdx.x;
    const int r = blockIdx.x;
    const float* srow = sims + (size_t)r * NPAD;

    for (int i = tid; i < 4 * HBINS; i += 256) hist[i >> 11][i & (HBINS - 1)] = 0;
    if (tid == 0) s_cnt = 0;
    __syncthreads();

    for (int i = tid * 4; i < NTRAIN; i += 1024) {
        float4 v = *reinterpret_cast<const float4*>(&srow[i]);
        float vv[4] = {v.x, v.y, v.z, v.w};
        #pragma unroll
        for (int j = 0; j < 4; ++j) {
            int b = (int)fminf(fmaxf((vv[j] - HLO) * HSC, 0.0f), 2047.0f);
            atomicAdd(&hist[tid & 3][b], 1);
        }
    }
    __syncthreads();
    for (int i = tid; i < HBINS; i += 256)
        hist[0][i] += hist[1][i] + hist[2][i] + hist[3][i];
    __syncthreads();
    if (tid == 0) {
        int cum = 0, b = HBINS - 1;
        for (; b > 0; --b) { if (cum + hist[0][b] >= MAXK) break; cum += hist[0][b]; }
        s_L = HLO + (float)b / HSC - MARGIN;   // bin lower edge minus margin
    }
    __syncthreads();
    const float Lv = s_L;

    for (int i = tid * 4; i < NTRAIN; i += 1024) {
        float4 v = *reinterpret_cast<const float4*>(&srow[i]);
        float vv[4] = {v.x, v.y, v.z, v.w};
        #pragma unroll
        for (int j = 0; j < 4; ++j) {
            if (vv[j] >= Lv && i + j < NTRAIN) {
                int p = atomicAdd(&s_cnt, 1);
                if (p < CAP2) ci[(size_t)r * CAP2 + p] = i + j;
            }
        }
    }
    __syncthreads();
    if (tid == 0) cc[r] = min(s_cnt, CAP2);
}

// ---------------- exact fp32 recompute of candidate dots ----------------
__global__ __launch_bounds__(256) void exact_refine(
    const float* __restrict__ A, const float* __restrict__ B,
    const int* __restrict__ ci, const int* __restrict__ cc, float* __restrict__ ev)
{
    __shared__ float sa[DIM];
    const int tid = threadIdx.x;
    const int r = blockIdx.x >> 2;
    const int part = blockIdx.x & 3;
    *reinterpret_cast<float4*>(&sa[tid * 4]) =
        *reinterpret_cast<const float4*>(&A[(size_t)r * DIM + tid * 4]);
    __syncthreads();
    const int lane = tid & 63;
    const int wave = tid >> 6;
    const int w = part * 4 + wave;
    const int M = min(cc[r], CAP2);

    for (int i = w; i < M; i += 16) {
        int idx = ci[(size_t)r * CAP2 + i];
        const float* brow = B + (size_t)idx * DIM;
        float s = 0.f;
        #pragma unroll
        for (int j = 0; j < 4; ++j) {
            float4 bvv = *reinterpret_cast<const float4*>(&brow[j * 256 + lane * 4]);
            float4 avv = *reinterpret_cast<const float4*>(&sa[j * 256 + lane * 4]);
            s = fmaf(avv.x, bvv.x, s);
            s = fmaf(avv.y, bvv.y, s);
            s = fmaf(avv.z, bvv.z, s);
            s = fmaf(avv.w, bvv.w, s);
        }
        #pragma unroll
        for (int m = 32; m >= 1; m >>= 1) s += __shfl_xor(s, m);
        if (lane == 0) ev[(size_t)r * CAP2 + i] = s;
    }
}

// ---------------- final: sort exact candidates, softmax top-200, cumulative scatter ----------------
__global__ __launch_bounds__(256) void finalize3(
    const float* __restrict__ ev, const int* __restrict__ ci, const int* __restrict__ cc,
    const int* __restrict__ labels, float* __restrict__ out)
{
    __shared__ float sval[CAP];
    __shared__ int   sidx[CAP];
    __shared__ float cls[NCLS];
    __shared__ float s_sum;
    const int tid = threadIdx.x;
    const int r = blockIdx.x;
    const int M = min(cc[r], CAP);   // expected ~210 << 512

    for (int i = tid; i < CAP; i += 256) {
        if (i < M) { sval[i] = ev[(size_t)r * CAP2 + i]; sidx[i] = ci[(size_t)r * CAP2 + i]; }
        else { sval[i] = -FLT_MAX; sidx[i] = 0x7FFFFFFF; }
    }
    __syncthreads();

    // bitonic sort, descending by (val desc, idx asc)
    for (int k = 2; k <= CAP; k <<= 1)
        for (int j = k >> 1; j > 0; j >>= 1) {
            for (int i = tid; i < CAP; i += 256) {
                int l = i ^ j;
                if (l > i) {
                    float av = sval[i], bv2 = sval[l];
                    int ai = sidx[i], bi = sidx[l];
                    bool iGTl = (av > bv2) || (av == bv2 && ai < bi);
                    bool sw = ((i & k) == 0) ? (!iGTl) : iGTl;
                    if (sw) { sval[i] = bv2; sval[l] = av; sidx[i] = bi; sidx[l] = ai; }
                }
            }
            __syncthreads();
        }

    float mx = sval[0];
    if (tid == 0) s_sum = 0.f;
    __syncthreads();
    float part = 0.f;
    for (int i = tid; i < MAXK; i += 256) {
        float e = expf((sval[i] - mx) * INV_T);
        sval[i] = e;
        part += e;
    }
    atomicAdd(&s_sum, part);
    __syncthreads();
    float inv = 1.f / s_sum;
    for (int i = tid; i < MAXK; i += 256) {
        sval[i] *= inv;
        sidx[i] = labels[sidx[i]];
    }
    for (int c = tid; c < NCLS; c += 256) cls[c] = 0.f;
    __syncthreads();

    const int KS[4] = {10, 20, 100, 200};
    int prev = 0;
    for (int s = 0; s < 4; ++s) {
        for (int i = prev + tid; i < KS[s]; i += 256)
            atomicAdd(&cls[sidx[i]], sval[i]);
        __syncthreads();
        float* o = out + ((size_t)s * NROWS + r) * NCLS;
        for (int c = tid; c < NCLS; c += 256) o[c] = cls[c];
        __syncthreads();
        prev = KS[s];
    }
}

// ---------------- host launcher ----------------
extern "C" void kernel_launch(void* const* d_in, const int* in_sizes, int n_in,
                              void* d_out, int out_size, void* d_ws, size_t ws_size,
                              hipStream_t stream)
{
    const float* A = (const float*)d_in[0];       // [512,1024]
    const float* B = (const float*)d_in[1];       // [100000,1024]
    const int* labels = (const int*)d_in[2];      // [100000]
    float* out = (float*)d_out;                   // [4,512,1000] f32

    char* ws = (char*)d_ws;
    size_t off = 0;
    auto carve = [&](size_t bytes) -> void* {
        void* p = ws + off;
        off = (off + bytes + 255) & ~(size_t)255;
        return p;
    };
    unsigned short* Ab = (unsigned short*)carve((size_t)NROWS * DIM * 2);     // 1 MB
    unsigned short* Bb = (unsigned short*)carve((size_t)NTRAIN * DIM * 2);    // 204.8 MB
    int*   ci = (int*)carve((size_t)NROWS * CAP2 * 4);                        // 2 MB
    float* ev = (float*)carve((size_t)NROWS * CAP2 * 4);                      // 2 MB
    int*   cc = (int*)carve((size_t)NROWS * 4);
    float* sims = (float*)carve((size_t)NROWS * NPAD * 4);                    // 205.5 MB

    // bf16 conversion
    convert_bf16<<<256, 256, 0, stream>>>(A, Ab, (long long)NROWS * DIM);
    convert_bf16<<<4096, 256, 0, stream>>>(B, Bb, (long long)NTRAIN * DIM);

    // full bf16 sims (single term), materialized
    gemm_bf<<<4 * NTILE, 256, 0, stream>>>(Ab, Bb, sims);

    // per-row top-200 superset via flat histogram + margin
    select_margin<<<NROWS, 256, 0, stream>>>(sims, ci, cc);

    // exact fp32 recompute of survivors
    exact_refine<<<NROWS * 4, 256, 0, stream>>>(A, B, ci, cc, ev);

    // exact sort + softmax + scatter
    finalize3<<<NROWS, 256, 0, stream>>>(ev, ci, cc, labels, out);
}

// Round 7
// 423.761 us; speedup vs baseline: 3.2385x; 1.1824x over previous
//
#include <hip/hip_runtime.h>
#include <float.h>
#include <math.h>

#define NROWS 512
#define DIM 1024
#define NTRAIN 100000
#define MAXK 200
#define NCLS 1000
#define CAP 512          // finalize working set
#define CAP2 1024        // candidate list per row (expected ~210)
#define INV_T (1.0f/0.07f)
#define NKS (DIM/32)     // 32 K-steps of BK=32
#define NTILE 784        // ceil(100000/128)
#define NPAD (NTILE*128) // 100352 padded sims stride
#define MARGIN 2.75f     // 2.5 (bf16-input sim error, ~25 sigma) + 0.25 bf16 storage ulp
#define HBINS 2048
#define HLO (-160.0f)
#define HSC 6.4f         // bins of width 0.15625 over [-160,160)

typedef short s16x8 __attribute__((ext_vector_type(8)));
typedef unsigned short u16x8 __attribute__((ext_vector_type(8)));
typedef float f32x4 __attribute__((ext_vector_type(4)));

__device__ __forceinline__ void gl_lds16(const void* g, void* l) {
    __builtin_amdgcn_global_load_lds(
        (const __attribute__((address_space(1))) unsigned int*)g,
        (__attribute__((address_space(3))) unsigned int*)l, 16, 0, 0);
}
__device__ __forceinline__ unsigned short f2bf(float x) {   // RTNE
    unsigned u = __float_as_uint(x);
    return (unsigned short)((u + 0x7FFFu + ((u >> 16) & 1u)) >> 16);
}
__device__ __forceinline__ float bf2f(unsigned short b) {
    return __uint_as_float(((unsigned)b) << 16);
}

// ---------------- fp32 -> bf16 ----------------
__global__ __launch_bounds__(256) void convert_bf16(
    const float* __restrict__ in, unsigned short* __restrict__ out, long long n)
{
    long long i0 = ((long long)blockIdx.x * 256 + threadIdx.x) * 8;
    long long stride = (long long)gridDim.x * 2048;
    for (long long i = i0; i < n; i += stride) {
        float4 v0 = *reinterpret_cast<const float4*>(&in[i]);
        float4 v1 = *reinterpret_cast<const float4*>(&in[i + 4]);
        u16x8 o;
        o[0] = f2bf(v0.x); o[1] = f2bf(v0.y); o[2] = f2bf(v0.z); o[3] = f2bf(v0.w);
        o[4] = f2bf(v1.x); o[5] = f2bf(v1.y); o[6] = f2bf(v1.z); o[7] = f2bf(v1.w);
        *reinterpret_cast<u16x8*>(&out[i]) = o;
    }
}

// ---------------- bf16 GEMM, depth-2 counted-vmcnt pipeline, bf16 sims out ----------------
// 128x128 tile, BK=32, 4 waves (64x64 each). 3 LDS buffers x (A 8KB + B 8KB) = 48KB.
// Per step: raw s_barrier preceded by s_waitcnt vmcnt(4) -> next step's 4 gl_lds stay
// in flight across the barrier (T3/T4). Packed-line staging + 2-bit XOR slot swizzle
// (SQ_LDS_BANK_CONFLICT == 0 verified in r5/r6).
__global__ __launch_bounds__(256) void gemm_bf(
    const unsigned short* __restrict__ Ab, const unsigned short* __restrict__ Bb,
    unsigned short* __restrict__ simsb)
{
    __shared__ __align__(16) unsigned short sm[3][2][4096];  // [buf][A,B][8KB]
    const int tid = threadIdx.x;
    const int lane = tid & 63;
    const int wave = tid >> 6;

    // bijective XCD swizzle (grid % 8 == 0), m-tile fastest for B-panel L2 reuse
    const int nwg = gridDim.x;
    const int wg = (blockIdx.x & 7) * (nwg >> 3) + (blockIdx.x >> 3);
    const int mt = wg & 3, nt = wg >> 2;
    const int m0 = mt * 128, n0 = nt * 128;
    const int wm = wave >> 1, wn = wave & 1;

    // staging geometry: instr i covers chunks [wave*64 + i*256, +64); lane -> base+lane
    size_t gA[2], gB[2];
    #pragma unroll
    for (int i = 0; i < 2; ++i) {
        int c = wave * 64 + i * 256 + lane;
        int rr = c >> 2, q = c & 3;
        int slot = q ^ ((rr >> 1) & 3);
        int brow = n0 + rr;
        if (brow > NTRAIN - 1) brow = NTRAIN - 1;   // pad cols clamp (never selected)
        gA[i] = (size_t)(m0 + rr) * DIM + slot * 8;
        gB[i] = (size_t)brow * DIM + slot * 8;
    }
    const int ldsb0 = (wave * 64) * 16;
    const int ldsb1 = (wave * 64 + 256) * 16;

    f32x4 acc[4][4] = {};

    auto stage = [&](int b, int k0) {
        char* base = (char*)&sm[b][0][0];
        gl_lds16(Ab + gA[0] + k0, base + 0 * 8192 + ldsb0);
        gl_lds16(Ab + gA[1] + k0, base + 0 * 8192 + ldsb1);
        gl_lds16(Bb + gB[0] + k0, base + 1 * 8192 + ldsb0);
        gl_lds16(Bb + gB[1] + k0, base + 1 * 8192 + ldsb1);
    };

    const int slot = lane >> 4;
    const int r16 = lane & 15;

    // prologue: two K-steps in flight
    stage(0, 0);
    stage(1, 32);

    for (int t = 0; t < NKS; ++t) {
        // wait: step-t loads done; step-(t+1) loads (4) remain in flight across barrier
        if (t + 1 < NKS) {
            asm volatile("s_waitcnt vmcnt(4)" ::: "memory");
        } else {
            asm volatile("s_waitcnt vmcnt(0)" ::: "memory");
        }
        __builtin_amdgcn_s_barrier();
        __builtin_amdgcn_sched_barrier(0);

        if (t + 2 < NKS) stage((t + 2) % 3, (t + 2) * 32);   // depth-2 prefetch

        const unsigned short* sa = &sm[t % 3][0][0];
        const unsigned short* sb = &sm[t % 3][1][0];

        s16x8 bv[4];
        #pragma unroll
        for (int n = 0; n < 4; ++n) {
            int rr = wn * 64 + n * 16 + r16;
            int cch = rr * 4 + (slot ^ ((rr >> 1) & 3));
            bv[n] = *reinterpret_cast<const s16x8*>(&sb[cch * 8]);
        }
        #pragma unroll
        for (int m = 0; m < 4; ++m) {
            int rr = wm * 64 + m * 16 + r16;
            int cch = rr * 4 + (slot ^ ((rr >> 1) & 3));
            s16x8 av = *reinterpret_cast<const s16x8*>(&sa[cch * 8]);
            #pragma unroll
            for (int n = 0; n < 4; ++n)
                acc[m][n] = __builtin_amdgcn_mfma_f32_16x16x32_bf16(av, bv[n], acc[m][n], 0, 0, 0);
        }
        // no trailing barrier: buf[t%3] is re-staged at step t+1, after ALL waves
        // passed barrier(t+1), i.e. after their step-t ds_reads landed in regs.
    }

    // epilogue: C/D layout col=lane&15, row=(lane>>4)*4+reg; bf16 store
    const int q4 = (lane >> 4) * 4;
    const int cL = lane & 15;
    #pragma unroll
    for (int m = 0; m < 4; ++m)
        #pragma unroll
        for (int j = 0; j < 4; ++j) {
            int orow = m0 + wm * 64 + m * 16 + q4 + j;
            unsigned short* dst = simsb + (size_t)orow * NPAD + n0 + wn * 64 + cL;
            #pragma unroll
            for (int n = 0; n < 4; ++n)
                dst[n * 16] = f2bf(acc[m][n][j]);
        }
}

// ---------------- per-row: flat histogram -> threshold-with-margin -> append ----------------
__global__ __launch_bounds__(512) void select_margin(
    const unsigned short* __restrict__ simsb, int* __restrict__ ci, int* __restrict__ cc)
{
    __shared__ int hist[4][HBINS];   // 32KB, 4 replicas to cut atomic collisions
    __shared__ float s_L;
    __shared__ int s_cnt;
    const int tid = threadIdx.x;
    const int r = blockIdx.x;
    const unsigned short* srow = simsb + (size_t)r * NPAD;

    for (int i = tid; i < 4 * HBINS; i += 512) hist[i >> 11][i & (HBINS - 1)] = 0;
    if (tid == 0) s_cnt = 0;
    __syncthreads();

    // NTRAIN % 8 == 0: loops never touch pad cols
    for (int i = tid * 8; i < NTRAIN; i += 4096) {
        u16x8 v = *reinterpret_cast<const u16x8*>(&srow[i]);
        #pragma unroll
        for (int j = 0; j < 8; ++j) {
            int b = (int)fminf(fmaxf((bf2f(v[j]) - HLO) * HSC, 0.0f), 2047.0f);
            atomicAdd(&hist[tid & 3][b], 1);
        }
    }
    __syncthreads();
    for (int i = tid; i < HBINS; i += 512)
        hist[0][i] += hist[1][i] + hist[2][i] + hist[3][i];
    __syncthreads();
    if (tid == 0) {
        int cum = 0, b = HBINS - 1;
        for (; b > 0; --b) { if (cum + hist[0][b] >= MAXK) break; cum += hist[0][b]; }
        s_L = HLO + (float)b / HSC - MARGIN;   // bin lower edge minus margin
    }
    __syncthreads();
    const float Lv = s_L;

    for (int i = tid * 8; i < NTRAIN; i += 4096) {
        u16x8 v = *reinterpret_cast<const u16x8*>(&srow[i]);
        #pragma unroll
        for (int j = 0; j < 8; ++j) {
            if (bf2f(v[j]) >= Lv) {
                int p = atomicAdd(&s_cnt, 1);
                if (p < CAP2) ci[(size_t)r * CAP2 + p] = i + j;
            }
        }
    }
    __syncthreads();
    if (tid == 0) cc[r] = min(s_cnt, CAP2);
}

// ---------------- exact fp32 recompute of candidate dots ----------------
__global__ __launch_bounds__(256) void exact_refine(
    const float* __restrict__ A, const float* __restrict__ B,
    const int* __restrict__ ci, const int* __restrict__ cc, float* __restrict__ ev)
{
    __shared__ float sa[DIM];
    const int tid = threadIdx.x;
    const int r = blockIdx.x >> 2;
    const int part = blockIdx.x & 3;
    *reinterpret_cast<float4*>(&sa[tid * 4]) =
        *reinterpret_cast<const float4*>(&A[(size_t)r * DIM + tid * 4]);
    __syncthreads();
    const int lane = tid & 63;
    const int wave = tid >> 6;
    const int w = part * 4 + wave;
    const int M = min(cc[r], CAP2);

    for (int i = w; i < M; i += 16) {
        int idx = ci[(size_t)r * CAP2 + i];
        const float* brow = B + (size_t)idx * DIM;
        float s = 0.f;
        #pragma unroll
        for (int j = 0; j < 4; ++j) {
            float4 bvv = *reinterpret_cast<const float4*>(&brow[j * 256 + lane * 4]);
            float4 avv = *reinterpret_cast<const float4*>(&sa[j * 256 + lane * 4]);
            s = fmaf(avv.x, bvv.x, s);
            s = fmaf(avv.y, bvv.y, s);
            s = fmaf(avv.z, bvv.z, s);
            s = fmaf(avv.w, bvv.w, s);
        }
        #pragma unroll
        for (int m = 32; m >= 1; m >>= 1) s += __shfl_xor(s, m);
        if (lane == 0) ev[(size_t)r * CAP2 + i] = s;
    }
}

// ---------------- final: sort exact candidates, softmax top-200, cumulative scatter ----------------
__global__ __launch_bounds__(256) void finalize3(
    const float* __restrict__ ev, const int* __restrict__ ci, const int* __restrict__ cc,
    const int* __restrict__ labels, float* __restrict__ out)
{
    __shared__ float sval[CAP];
    __shared__ int   sidx[CAP];
    __shared__ float cls[NCLS];
    __shared__ float s_sum;
    const int tid = threadIdx.x;
    const int r = blockIdx.x;
    const int M = min(cc[r], CAP);   // expected ~210 << 512

    for (int i = tid; i < CAP; i += 256) {
        if (i < M) { sval[i] = ev[(size_t)r * CAP2 + i]; sidx[i] = ci[(size_t)r * CAP2 + i]; }
        else { sval[i] = -FLT_MAX; sidx[i] = 0x7FFFFFFF; }
    }
    __syncthreads();

    // bitonic sort, descending by (val desc, idx asc)
    for (int k = 2; k <= CAP; k <<= 1)
        for (int j = k >> 1; j > 0; j >>= 1) {
            for (int i = tid; i < CAP; i += 256) {
                int l = i ^ j;
                if (l > i) {
                    float av = sval[i], bv2 = sval[l];
                    int ai = sidx[i], bi = sidx[l];
                    bool iGTl = (av > bv2) || (av == bv2 && ai < bi);
                    bool sw = ((i & k) == 0) ? (!iGTl) : iGTl;
                    if (sw) { sval[i] = bv2; sval[l] = av; sidx[i] = bi; sidx[l] = ai; }
                }
            }
            __syncthreads();
        }

    float mx = sval[0];
    if (tid == 0) s_sum = 0.f;
    __syncthreads();
    float part = 0.f;
    for (int i = tid; i < MAXK; i += 256) {
        float e = expf((sval[i] - mx) * INV_T);
        sval[i] = e;
        part += e;
    }
    atomicAdd(&s_sum, part);
    __syncthreads();
    float inv = 1.f / s_sum;
    for (int i = tid; i < MAXK; i += 256) {
        sval[i] *= inv;
        sidx[i] = labels[sidx[i]];
    }
    for (int c = tid; c < NCLS; c += 256) cls[c] = 0.f;
    __syncthreads();

    const int KS[4] = {10, 20, 100, 200};
    int prev = 0;
    for (int s = 0; s < 4; ++s) {
        for (int i = prev + tid; i < KS[s]; i += 256)
            atomicAdd(&cls[sidx[i]], sval[i]);
        __syncthreads();
        float* o = out + ((size_t)s * NROWS + r) * NCLS;
        for (int c = tid; c < NCLS; c += 256) o[c] = cls[c];
        __syncthreads();
        prev = KS[s];
    }
}

// ---------------- host launcher ----------------
extern "C" void kernel_launch(void* const* d_in, const int* in_sizes, int n_in,
                              void* d_out, int out_size, void* d_ws, size_t ws_size,
                              hipStream_t stream)
{
    const float* A = (const float*)d_in[0];       // [512,1024]
    const float* B = (const float*)d_in[1];       // [100000,1024]
    const int* labels = (const int*)d_in[2];      // [100000]
    float* out = (float*)d_out;                   // [4,512,1000] f32

    char* ws = (char*)d_ws;
    size_t off = 0;
    auto carve = [&](size_t bytes) -> void* {
        void* p = ws + off;
        off = (off + bytes + 255) & ~(size_t)255;
        return p;
    };
    unsigned short* Ab = (unsigned short*)carve((size_t)NROWS * DIM * 2);     // 1 MB
    unsigned short* Bb = (unsigned short*)carve((size_t)NTRAIN * DIM * 2);    // 204.8 MB
    int*   ci = (int*)carve((size_t)NROWS * CAP2 * 4);                        // 2 MB
    float* ev = (float*)carve((size_t)NROWS * CAP2 * 4);                      // 2 MB
    int*   cc = (int*)carve((size_t)NROWS * 4);
    unsigned short* simsb = (unsigned short*)carve((size_t)NROWS * NPAD * 2); // 102.8 MB

    // bf16 conversion
    convert_bf16<<<128, 256, 0, stream>>>(A, Ab, (long long)NROWS * DIM);
    convert_bf16<<<4096, 256, 0, stream>>>(B, Bb, (long long)NTRAIN * DIM);

    // full bf16 sims (single term), materialized as bf16
    gemm_bf<<<4 * NTILE, 256, 0, stream>>>(Ab, Bb, simsb);

    // per-row top-200 superset via flat histogram + margin
    select_margin<<<NROWS, 512, 0, stream>>>(simsb, ci, cc);

    // exact fp32 recompute of survivors
    exact_refine<<<NROWS * 4, 256, 0, stream>>>(A, B, ci, cc, ev);

    // exact sort + softmax + scatter
    finalize3<<<NROWS, 256, 0, stream>>>(ev, ci, cc, labels, out);
}

// Round 8
// 392.712 us; speedup vs baseline: 3.4946x; 1.0791x over previous
//
#include <hip/hip_runtime.h>
#include <float.h>
#include <math.h>

#define NROWS 512
#define DIM 1024
#define NTRAIN 100000
#define MAXK 200
#define NCLS 1000
#define CAP 512          // finalize working set
#define CAP2 1024        // candidate list per row (expected ~260)
#define INV_T (1.0f/0.07f)
#define NKS (DIM/32)     // 32 K-steps of BK=32
#define NTILE 784        // ceil(100000/128)
#define NPAD (NTILE*128) // 100352 padded sims stride
#define MARGIN 3.0f      // ~20 sigma of bf16-RTZ sim error + 0.25 storage ulp
#define HBINS 2048
#define HLO (-160.0f)
#define HSC 6.4f         // bins of width 0.15625 over [-160,160)

typedef short s16x8 __attribute__((ext_vector_type(8)));
typedef unsigned short u16x8 __attribute__((ext_vector_type(8)));
typedef unsigned int u32x4 __attribute__((ext_vector_type(4)));
typedef float f32x4 __attribute__((ext_vector_type(4)));

__device__ __forceinline__ void gl_lds16(const void* g, void* l) {
    __builtin_amdgcn_global_load_lds(
        (const __attribute__((address_space(1))) unsigned int*)g,
        (__attribute__((address_space(3))) unsigned int*)l, 16, 0, 0);
}
__device__ __forceinline__ unsigned short f2bf(float x) {   // RTNE
    unsigned u = __float_as_uint(x);
    return (unsigned short)((u + 0x7FFFu + ((u >> 16) & 1u)) >> 16);
}
__device__ __forceinline__ float bf2f(unsigned short b) {
    return __uint_as_float(((unsigned)b) << 16);
}

// ---------------- fp32 -> bf16 (A only; B fused into GEMM) ----------------
__global__ __launch_bounds__(256) void convert_bf16(
    const float* __restrict__ in, unsigned short* __restrict__ out, long long n)
{
    long long i0 = ((long long)blockIdx.x * 256 + threadIdx.x) * 8;
    long long stride = (long long)gridDim.x * 2048;
    for (long long i = i0; i < n; i += stride) {
        float4 v0 = *reinterpret_cast<const float4*>(&in[i]);
        float4 v1 = *reinterpret_cast<const float4*>(&in[i + 4]);
        u16x8 o;
        o[0] = f2bf(v0.x); o[1] = f2bf(v0.y); o[2] = f2bf(v0.z); o[3] = f2bf(v0.w);
        o[4] = f2bf(v1.x); o[5] = f2bf(v1.y); o[6] = f2bf(v1.z); o[7] = f2bf(v1.w);
        *reinterpret_cast<u16x8*>(&out[i]) = o;
    }
}

// ---------------- fused-convert bf16 GEMM, depth-2 counted-vmcnt pipeline ----------------
// 128x128 tile, BK=32, 4 waves. Per buf: A bf16 8KB (chunks c=rr*4+(q^((rr>>1)&3)))
// + B fp32 16KB (chunks c=rr*8+(q^(rr&7))). B packed to bf16 in-register via v_perm
// (RTZ). 3 bufs x 24KB = 72KB. s_waitcnt vmcnt(6): next step's 6 loads span the barrier.
__global__ __launch_bounds__(256) void gemm_fused(
    const unsigned short* __restrict__ Ab, const float* __restrict__ B,
    unsigned short* __restrict__ simsb)
{
    __shared__ __align__(16) char sm[3][24576];   // [buf][A 8KB | B 16KB]
    const int tid = threadIdx.x;
    const int lane = tid & 63;
    const int wave = tid >> 6;

    // bijective XCD swizzle (grid % 8 == 0), m-tile fastest for B-panel L2 reuse
    const int nwg = gridDim.x;
    const int wg = (blockIdx.x & 7) * (nwg >> 3) + (blockIdx.x >> 3);
    const int mt = wg & 3, nt = wg >> 2;
    const int m0 = mt * 128, n0 = nt * 128;
    const int wm = wave >> 1, wn = wave & 1;

    // A staging: 512 chunks of 16B; instr i covers chunks wave*64 + i*256 + lane
    size_t gA[2];
    #pragma unroll
    for (int i = 0; i < 2; ++i) {
        int c = wave * 64 + i * 256 + lane;
        int rr = c >> 2, q = c & 3;
        int slot = q ^ ((rr >> 1) & 3);
        gA[i] = (size_t)(m0 + rr) * DIM + slot * 8;   // bf16 elements
    }
    const int ldsA0 = (wave * 64) * 16;
    const int ldsA1 = (wave * 64 + 256) * 16;

    // B staging (fp32): 1024 chunks of 16B; instr i covers chunks wave*256 + i*64 + lane
    size_t gB[4];
    #pragma unroll
    for (int i = 0; i < 4; ++i) {
        int c = wave * 256 + i * 64 + lane;
        int rr = c >> 3, q = c & 7;
        int slot = q ^ (rr & 7);
        int brow = n0 + rr;
        if (brow > NTRAIN - 1) brow = NTRAIN - 1;     // pad cols clamp (never selected)
        gB[i] = (size_t)brow * DIM + slot * 4;        // fp32 elements
    }
    const int ldsB[4] = { 8192 + (wave * 256) * 16, 8192 + (wave * 256 + 64) * 16,
                          8192 + (wave * 256 + 128) * 16, 8192 + (wave * 256 + 192) * 16 };

    f32x4 acc[4][4] = {};

    auto stage = [&](int b, int k0) {
        char* base = &sm[b][0];
        gl_lds16(Ab + gA[0] + k0, base + ldsA0);
        gl_lds16(Ab + gA[1] + k0, base + ldsA1);
        #pragma unroll
        for (int i = 0; i < 4; ++i)
            gl_lds16(B + gB[i] + k0, base + ldsB[i]);
    };

    const int qq = lane >> 4;     // k-quarter
    const int r16 = lane & 15;

    // prologue: two K-steps in flight
    stage(0, 0);
    stage(1, 32);

    for (int t = 0; t < NKS; ++t) {
        if (t + 1 < NKS) {
            asm volatile("s_waitcnt vmcnt(6)" ::: "memory");
        } else {
            asm volatile("s_waitcnt vmcnt(0)" ::: "memory");
        }
        __builtin_amdgcn_s_barrier();
        __builtin_amdgcn_sched_barrier(0);

        if (t + 2 < NKS) stage((t + 2) % 3, (t + 2) * 32);   // depth-2 prefetch

        const char* sa = &sm[t % 3][0];
        const char* sbB = &sm[t % 3][8192];

        // B frags: read 2 float4 (fp32) per frag, pack to bf16 via v_perm (RTZ)
        s16x8 bv[4];
        #pragma unroll
        for (int n = 0; n < 4; ++n) {
            int rr = wn * 64 + n * 16 + r16;
            const char* rowb = sbB + (rr * 8) * 16;
            int c0 = (2 * qq) ^ (rr & 7);
            int c1 = (2 * qq + 1) ^ (rr & 7);
            u32x4 fa = *reinterpret_cast<const u32x4*>(rowb + c0 * 16);
            u32x4 fb = *reinterpret_cast<const u32x4*>(rowb + c1 * 16);
            unsigned w0 = __builtin_amdgcn_perm(fa[1], fa[0], 0x07060302u);
            unsigned w1 = __builtin_amdgcn_perm(fa[3], fa[2], 0x07060302u);
            unsigned w2 = __builtin_amdgcn_perm(fb[1], fb[0], 0x07060302u);
            unsigned w3 = __builtin_amdgcn_perm(fb[3], fb[2], 0x07060302u);
            u32x4 packed = { w0, w1, w2, w3 };
            bv[n] = __builtin_bit_cast(s16x8, packed);
        }
        #pragma unroll
        for (int m = 0; m < 4; ++m) {
            int rr = wm * 64 + m * 16 + r16;
            int cch = rr * 4 + (qq ^ ((rr >> 1) & 3));
            s16x8 av = *reinterpret_cast<const s16x8*>(sa + cch * 16);
            #pragma unroll
            for (int n = 0; n < 4; ++n)
                acc[m][n] = __builtin_amdgcn_mfma_f32_16x16x32_bf16(av, bv[n], acc[m][n], 0, 0, 0);
        }
        // no trailing barrier: buf[t%3] re-staged only at step t+1 (after barrier t+1),
        // by which time every wave's step-t ds_reads have landed in registers.
    }

    // epilogue: C/D layout col=lane&15, row=(lane>>4)*4+reg; bf16 store
    const int q4 = (lane >> 4) * 4;
    const int cL = lane & 15;
    #pragma unroll
    for (int m = 0; m < 4; ++m)
        #pragma unroll
        for (int j = 0; j < 4; ++j) {
            int orow = m0 + wm * 64 + m * 16 + q4 + j;
            unsigned short* dst = simsb + (size_t)orow * NPAD + n0 + wn * 64 + cL;
            #pragma unroll
            for (int n = 0; n < 4; ++n)
                dst[n * 16] = f2bf(acc[m][n][j]);
        }
}

// ---------------- per-row: flat histogram -> threshold-with-margin -> append ----------------
__global__ __launch_bounds__(512) void select_margin(
    const unsigned short* __restrict__ simsb, int* __restrict__ ci, int* __restrict__ cc)
{
    __shared__ int hist[4][HBINS];   // 32KB, 4 replicas to cut atomic collisions
    __shared__ float s_L;
    __shared__ int s_cnt;
    const int tid = threadIdx.x;
    const int r = blockIdx.x;
    const unsigned short* srow = simsb + (size_t)r * NPAD;

    for (int i = tid; i < 4 * HBINS; i += 512) hist[i >> 11][i & (HBINS - 1)] = 0;
    if (tid == 0) s_cnt = 0;
    __syncthreads();

    // NTRAIN % 8 == 0: loops never touch pad cols
    for (int i = tid * 8; i < NTRAIN; i += 4096) {
        u16x8 v = *reinterpret_cast<const u16x8*>(&srow[i]);
        #pragma unroll
        for (int j = 0; j < 8; ++j) {
            int b = (int)fminf(fmaxf((bf2f(v[j]) - HLO) * HSC, 0.0f), 2047.0f);
            atomicAdd(&hist[tid & 3][b], 1);
        }
    }
    __syncthreads();
    for (int i = tid; i < HBINS; i += 512)
        hist[0][i] += hist[1][i] + hist[2][i] + hist[3][i];
    __syncthreads();
    if (tid == 0) {
        int cum = 0, b = HBINS - 1;
        for (; b > 0; --b) { if (cum + hist[0][b] >= MAXK) break; cum += hist[0][b]; }
        s_L = HLO + (float)b / HSC - MARGIN;   // bin lower edge minus margin
    }
    __syncthreads();
    const float Lv = s_L;

    for (int i = tid * 8; i < NTRAIN; i += 4096) {
        u16x8 v = *reinterpret_cast<const u16x8*>(&srow[i]);
        #pragma unroll
        for (int j = 0; j < 8; ++j) {
            if (bf2f(v[j]) >= Lv) {
                int p = atomicAdd(&s_cnt, 1);
                if (p < CAP2) ci[(size_t)r * CAP2 + p] = i + j;
            }
        }
    }
    __syncthreads();
    if (tid == 0) cc[r] = min(s_cnt, CAP2);
}

// ---------------- exact fp32 recompute of candidate dots ----------------
__global__ __launch_bounds__(256) void exact_refine(
    const float* __restrict__ A, const float* __restrict__ B,
    const int* __restrict__ ci, const int* __restrict__ cc, float* __restrict__ ev)
{
    __shared__ float sa[DIM];
    const int tid = threadIdx.x;
    const int r = blockIdx.x >> 2;
    const int part = blockIdx.x & 3;
    *reinterpret_cast<float4*>(&sa[tid * 4]) =
        *reinterpret_cast<const float4*>(&A[(size_t)r * DIM + tid * 4]);
    __syncthreads();
    const int lane = tid & 63;
    const int wave = tid >> 6;
    const int w = part * 4 + wave;
    const int M = min(cc[r], CAP2);

    for (int i = w; i < M; i += 16) {
        int idx = ci[(size_t)r * CAP2 + i];
        const float* brow = B + (size_t)idx * DIM;
        float s = 0.f;
        #pragma unroll
        for (int j = 0; j < 4; ++j) {
            float4 bvv = *reinterpret_cast<const float4*>(&brow[j * 256 + lane * 4]);
            float4 avv = *reinterpret_cast<const float4*>(&sa[j * 256 + lane * 4]);
            s = fmaf(avv.x, bvv.x, s);
            s = fmaf(avv.y, bvv.y, s);
            s = fmaf(avv.z, bvv.z, s);
            s = fmaf(avv.w, bvv.w, s);
        }
        #pragma unroll
        for (int m = 32; m >= 1; m >>= 1) s += __shfl_xor(s, m);
        if (lane == 0) ev[(size_t)r * CAP2 + i] = s;
    }
}

// ---------------- final: sort exact candidates, softmax top-200, cumulative scatter ----------------
__global__ __launch_bounds__(256) void finalize3(
    const float* __restrict__ ev, const int* __restrict__ ci, const int* __restrict__ cc,
    const int* __restrict__ labels, float* __restrict__ out)
{
    __shared__ float sval[CAP];
    __shared__ int   sidx[CAP];
    __shared__ float cls[NCLS];
    __shared__ float s_sum;
    const int tid = threadIdx.x;
    const int r = blockIdx.x;
    const int M = min(cc[r], CAP);   // expected ~260 << 512

    for (int i = tid; i < CAP; i += 256) {
        if (i < M) { sval[i] = ev[(size_t)r * CAP2 + i]; sidx[i] = ci[(size_t)r * CAP2 + i]; }
        else { sval[i] = -FLT_MAX; sidx[i] = 0x7FFFFFFF; }
    }
    __syncthreads();

    // bitonic sort, descending by (val desc, idx asc)
    for (int k = 2; k <= CAP; k <<= 1)
        for (int j = k >> 1; j > 0; j >>= 1) {
            for (int i = tid; i < CAP; i += 256) {
                int l = i ^ j;
                if (l > i) {
                    float av = sval[i], bv2 = sval[l];
                    int ai = sidx[i], bi = sidx[l];
                    bool iGTl = (av > bv2) || (av == bv2 && ai < bi);
                    bool sw = ((i & k) == 0) ? (!iGTl) : iGTl;
                    if (sw) { sval[i] = bv2; sval[l] = av; sidx[i] = bi; sidx[l] = ai; }
                }
            }
            __syncthreads();
        }

    float mx = sval[0];
    if (tid == 0) s_sum = 0.f;
    __syncthreads();
    float part = 0.f;
    for (int i = tid; i < MAXK; i += 256) {
        float e = expf((sval[i] - mx) * INV_T);
        sval[i] = e;
        part += e;
    }
    atomicAdd(&s_sum, part);
    __syncthreads();
    float inv = 1.f / s_sum;
    for (int i = tid; i < MAXK; i += 256) {
        sval[i] *= inv;
        sidx[i] = labels[sidx[i]];
    }
    for (int c = tid; c < NCLS; c += 256) cls[c] = 0.f;
    __syncthreads();

    const int KS[4] = {10, 20, 100, 200};
    int prev = 0;
    for (int s = 0; s < 4; ++s) {
        for (int i = prev + tid; i < KS[s]; i += 256)
            atomicAdd(&cls[sidx[i]], sval[i]);
        __syncthreads();
        float* o = out + ((size_t)s * NROWS + r) * NCLS;
        for (int c = tid; c < NCLS; c += 256) o[c] = cls[c];
        __syncthreads();
        prev = KS[s];
    }
}

// ---------------- host launcher ----------------
extern "C" void kernel_launch(void* const* d_in, const int* in_sizes, int n_in,
                              void* d_out, int out_size, void* d_ws, size_t ws_size,
                              hipStream_t stream)
{
    const float* A = (const float*)d_in[0];       // [512,1024]
    const float* B = (const float*)d_in[1];       // [100000,1024]
    const int* labels = (const int*)d_in[2];      // [100000]
    float* out = (float*)d_out;                   // [4,512,1000] f32

    char* ws = (char*)d_ws;
    size_t off = 0;
    auto carve = [&](size_t bytes) -> void* {
        void* p = ws + off;
        off = (off + bytes + 255) & ~(size_t)255;
        return p;
    };
    unsigned short* Ab = (unsigned short*)carve((size_t)NROWS * DIM * 2);     // 1 MB
    int*   ci = (int*)carve((size_t)NROWS * CAP2 * 4);                        // 2 MB
    float* ev = (float*)carve((size_t)NROWS * CAP2 * 4);                      // 2 MB
    int*   cc = (int*)carve((size_t)NROWS * 4);
    unsigned short* simsb = (unsigned short*)carve((size_t)NROWS * NPAD * 2); // 102.8 MB

    // A -> bf16 (tiny)
    convert_bf16<<<128, 256, 0, stream>>>(A, Ab, (long long)NROWS * DIM);

    // full bf16 sims with fused fp32->bf16 B conversion, materialized as bf16
    gemm_fused<<<4 * NTILE, 256, 0, stream>>>(Ab, B, simsb);

    // per-row top-200 superset via flat histogram + margin
    select_margin<<<NROWS, 512, 0, stream>>>(simsb, ci, cc);

    // exact fp32 recompute of survivors
    exact_refine<<<NROWS * 4, 256, 0, stream>>>(A, B, ci, cc, ev);

    // exact sort + softmax + scatter
    finalize3<<<NROWS, 256, 0, stream>>>(ev, ci, cc, labels, out);
}